// Round 5
// baseline (120.619 us; speedup 1.0000x reference)
//
#include <hip/hip_runtime.h>

#define TK 80    // TOKEN_DIM
#define TN 384   // EMB_DIM
#define BM 64    // rows per block

typedef __attribute__((ext_vector_type(8)))  __bf16 bf16x8;
typedef __attribute__((ext_vector_type(4)))  __bf16 bf16x4;
typedef __attribute__((ext_vector_type(16))) float  f32x16;

// f32 -> bf16 via compiler-native converts (v_cvt_pk_bf16_f32 pairs)
__device__ __forceinline__ bf16x8 pack8(float4 f0, float4 f1) {
    bf16x8 r;
    r[0] = (__bf16)f0.x; r[1] = (__bf16)f0.y;
    r[2] = (__bf16)f0.z; r[3] = (__bf16)f0.w;
    r[4] = (__bf16)f1.x; r[5] = (__bf16)f1.y;
    r[6] = (__bf16)f1.z; r[7] = (__bf16)f1.w;
    return r;
}

// ---------------------------------------------------------------------------
// Fused TokenEmbedder.
// Block = 256 threads (4 waves), 64 out rows; wave w owns out cols [96w,96w+96).
// Phase 1: stage feat tile (64x80 f32, 20 KB) into LDS *as bf16 in MFMA
//          fragment order*: sA[mt][ks][khalf][r][j]. Global reads are fully
//          coalesced (thread t reads float4 #t); frag ds_read_b128 is
//          lane-contiguous -> conflict-free.
// Phase 2: per wave, nt-outer loop (3 col tiles of 32):
//          load+convert 5 W frags, 10 MFMAs into 2 accs, store epilogue.
// MFMA orientation (verified rounds 2/4): D col = lane&31 = out col ->
// stores are two 128-B contiguous segments per wave-store.
// Also emits the 3 passthrough outputs (amask/bidx; block 0: gidx).
// ---------------------------------------------------------------------------
__global__ __launch_bounds__(256, 4) void tok_fused(
    const float* __restrict__ feat,
    const unsigned char* __restrict__ amask,
    const int* __restrict__ gidx,
    const int* __restrict__ bidx,
    const float* __restrict__ W,
    const float* __restrict__ bias,
    const float* __restrict__ cls,
    float* __restrict__ out,
    float* __restrict__ out_amask,
    float* __restrict__ out_gidx,
    float* __restrict__ out_bidx,
    int B, int T)
{
    __shared__ __align__(16) __bf16 sA[2 * 5 * 2 * 32 * 8];   // 10 KB

    const int tid   = threadIdx.x;
    const int lane  = tid & 63;
    const int wave  = tid >> 6;
    const int row0  = blockIdx.x * BM;
    const int colb  = wave * 96;
    const int lrow  = lane & 31;   // A-row (out row) / B-col (out col) in tile
    const int khalf = lane >> 5;   // 8-wide k-half selector

    // ---- amask storage detection (bool bytes vs int32): probe first 1 KB
    const unsigned int* w32 = (const unsigned int*)amask;
    unsigned int wprobe = w32[tid & 255];
    int bytemode = __syncthreads_or((int)((wprobe & 0xFFFFFF00u) != 0u));

    // ---- passthrough outputs
    if (tid < BM) {
        int r = row0 + tid;
        out_amask[r] = bytemode ? (float)amask[r] : (float)(w32[r] & 1u);
        out_bidx[r]  = (float)bidx[r];
    }
    if (blockIdx.x == 0 && tid < B) out_gidx[tid] = (float)gidx[tid];

    // ---- mask row vector: lane holds mask of row row0+lane (shfl later)
    float mv;
    {
        int r = row0 + lane;
        mv = bytemode ? (float)amask[r] : (float)(w32[r] & 1u);
    }

    // ---- Phase 1: coalesced stage of feat tile -> LDS (bf16, fragment order)
    // linear idx over 1280 float4s: rg = row in tile, q = which 4-dword group
    // k = q*4 + 0..3 -> ks = q>>2, khalf = (q>>1)&1, jq = q&1
    #pragma unroll
    for (int i = 0; i < 5; ++i) {
        int idx = tid + i * 256;
        float4 v = *(const float4*)(feat + (size_t)row0 * TK + (size_t)idx * 4);
        int rg = idx / 20;
        int q  = idx % 20;
        int ks = q >> 2, kh = (q >> 1) & 1, jq = q & 1;
        int off = (((((rg >> 5) * 5 + ks) * 2 + kh) * 32 + (rg & 31)) * 8) + jq * 4;
        bf16x4 c;
        c[0] = (__bf16)v.x; c[1] = (__bf16)v.y;
        c[2] = (__bf16)v.z; c[3] = (__bf16)v.w;
        *(bf16x4*)&sA[off] = c;
    }
    __syncthreads();

    // ---- A fragments: lane-contiguous LDS reads (conflict-free)
    bf16x8 af[2][5];
    #pragma unroll
    for (int mt = 0; mt < 2; ++mt)
        #pragma unroll
        for (int ks = 0; ks < 5; ++ks)
            af[mt][ks] = *(const bf16x8*)
                &sA[((((mt * 5 + ks) * 2 + khalf) * 32) + lrow) * 8];

    const bool blkcls = (row0 % T) == 0;   // cls row only at rlocal==0 (BM|T)

    // ---- Phase 2: nt-outer loop keeps only 2 accumulators live
    #pragma unroll
    for (int nt = 0; nt < 3; ++nt) {
        const int c = colb + nt * 32 + lrow;

        bf16x8 wf[5];
        #pragma unroll
        for (int ks = 0; ks < 5; ++ks) {
            const float* p = W + (size_t)c * TK + ks * 16 + khalf * 8;
            wf[ks] = pack8(*(const float4*)p, *(const float4*)(p + 4));
        }

        f32x16 acc0 = (f32x16)0.0f, acc1 = (f32x16)0.0f;
        #pragma unroll
        for (int ks = 0; ks < 5; ++ks) {
            acc0 = __builtin_amdgcn_mfma_f32_32x32x16_bf16(af[0][ks], wf[ks], acc0, 0, 0, 0);
            acc1 = __builtin_amdgcn_mfma_f32_32x32x16_bf16(af[1][ks], wf[ks], acc1, 0, 0, 0);
        }

        const float bvn = bias[c];
        const float cvn = cls[c];

        // epilogue: row = row0 + mt*32 + 4*khalf + (reg&3) + 8*(reg>>2)
        #pragma unroll
        for (int mt = 0; mt < 2; ++mt) {
            const f32x16& a = mt ? acc1 : acc0;
            #pragma unroll
            for (int reg = 0; reg < 16; ++reg) {
                const int rlocal = mt * 32 + 4 * khalf + (reg & 3) + 8 * (reg >> 2);
                const float m = __shfl(mv, rlocal);
                float v = m * (a[reg] + bvn);
                if (blkcls & (rlocal == 0)) v = cvn;
                out[(size_t)(row0 + rlocal) * TN + c] = v;
            }
        }
    }
}

extern "C" void kernel_launch(void* const* d_in, const int* in_sizes, int n_in,
                              void* d_out, int out_size, void* d_ws, size_t ws_size,
                              hipStream_t stream) {
    const float*         feat  = (const float*)d_in[0];
    const unsigned char* amask = (const unsigned char*)d_in[1];
    const int*           gidx  = (const int*)d_in[2];
    const int*           bidx  = (const int*)d_in[3];
    const float*         W     = (const float*)d_in[4];
    const float*         bias  = (const float*)d_in[5];
    const float*         cls   = (const float*)d_in[6];

    const int BT = in_sizes[1];        // B*T rows (131072)
    const int B  = in_sizes[2];        // 16
    const int T  = BT / B;             // 8192

    float* out       = (float*)d_out;                  // [BT, 384]
    float* out_amask = out + (size_t)BT * TN;          // [BT]
    float* out_gidx  = out_amask + BT;                 // [B]
    float* out_bidx  = out_gidx + B;                   // [BT]

    tok_fused<<<BT / BM, 256, 0, stream>>>(
        feat, amask, gidx, bidx, W, bias, cls,
        out, out_amask, out_gidx, out_bidx, B, T);
}